// Round 3
// baseline (2154.925 us; speedup 1.0000x reference)
//
#include <hip/hip_runtime.h>
#include <math.h>

static constexpr int DIM = 512;   // input feature dim
static constexpr int H   = 16;    // hidden dim
static constexpr int NC  = 40;    // classes

__device__ __forceinline__ float dot4(float4 a, float4 b) {
    return a.x * b.x + a.y * b.y + a.z * b.z + a.w * b.w;
}
__device__ __forceinline__ float waveMax(float v) {
#pragma unroll
    for (int m = 1; m <= 32; m <<= 1) v = fmaxf(v, __shfl_xor(v, m, 64));
    return v;
}
__device__ __forceinline__ float waveSum(float v) {
#pragma unroll
    for (int m = 1; m <= 32; m <<= 1) v += __shfl_xor(v, m, 64);
    return v;
}

// ---------------- CSR build ----------------
__global__ void k_hist(const int* __restrict__ dst, int* __restrict__ cnt, int E) {
    int stride = gridDim.x * blockDim.x;
    for (int i = blockIdx.x * blockDim.x + threadIdx.x; i < E; i += stride)
        atomicAdd(&cnt[dst[i]], 1);
}

// block-level sums of cnt (256 per block)
__global__ void __launch_bounds__(256) k_scan1(const int* __restrict__ cnt,
                                               int* __restrict__ bsum, int N) {
    __shared__ int sd[256];
    const int t = threadIdx.x;
    const int n = blockIdx.x * 256 + t;
    sd[t] = (n < N) ? cnt[n] : 0;
    __syncthreads();
    for (int s = 128; s > 0; s >>= 1) {
        if (t < s) sd[t] += sd[t + s];
        __syncthreads();
    }
    if (t == 0) bsum[blockIdx.x] = sd[0];
}

// single-block exclusive scan of the block sums (NB <= 512)
__global__ void __launch_bounds__(512) k_scan2(const int* __restrict__ bsum,
                                               int* __restrict__ bexc, int NB) {
    __shared__ int sd[512];
    const int t = threadIdx.x;
    const int v = (t < NB) ? bsum[t] : 0;
    sd[t] = v;
    __syncthreads();
    for (int ofs = 1; ofs < 512; ofs <<= 1) {
        const int x = sd[t];
        const int y = (t >= ofs) ? sd[t - ofs] : 0;
        __syncthreads();
        sd[t] = x + y;
        __syncthreads();
    }
    if (t < NB) bexc[t] = sd[t] - v;
}

// per-node offsets (node-ordered!), cursors, self-loop placement, bucket bases
__global__ void __launch_bounds__(256) k_scan3(int* __restrict__ cnt,
                                               const int* __restrict__ bexc,
                                               int* __restrict__ off,
                                               int* __restrict__ cursor,
                                               int* __restrict__ srcArr,
                                               int* __restrict__ pboff,
                                               int* __restrict__ bcur, int N) {
    __shared__ int sd[256];
    const int t = threadIdx.x;
    const int n = blockIdx.x * 256 + t;
    const int v = (n < N) ? cnt[n] : 0;
    sd[t] = v;
    __syncthreads();
    for (int ofs = 1; ofs < 256; ofs <<= 1) {
        const int x = sd[t];
        const int y = (t >= ofs) ? sd[t - ofs] : 0;
        __syncthreads();
        sd[t] = x + y;
        __syncthreads();
    }
    if (n < N) {
        const int pre = bexc[blockIdx.x] + sd[t] - v;  // exclusive prefix of raw counts
        const int o = pre + n;                          // + n self-loops before node n
        off[n] = o;
        cursor[n] = o + 1;      // slot 0 = self-loop
        srcArr[o] = n;          // place self-loop (ascending o -> coalesced-ish)
        cnt[n] = v + 1;         // total in-degree incl self-loop, for the props
        if ((n & 63) == 0) { pboff[n >> 6] = pre; bcur[n >> 6] = pre; }
    }
}

// partition edges into 64-node buckets; packed word = (src<<6) | (dst&63)
__global__ void k_binpass(const int* __restrict__ src, const int* __restrict__ dst,
                          int* __restrict__ bcur, int* __restrict__ pairs, int E) {
    int stride = gridDim.x * blockDim.x;
    for (int i = blockIdx.x * blockDim.x + threadIdx.x; i < E; i += stride) {
        const int d = dst[i];
        const int s = src[i];
        const int p = atomicAdd(&bcur[d >> 6], 1);
        pairs[p] = (s << 6) | (d & 63);
    }
}

// one block per bucket: LDS cursors, writes confined to the bucket's CSR slice
__global__ void __launch_bounds__(256) k_build(const int* __restrict__ pboff,
                                               const int* __restrict__ pairs,
                                               const int* __restrict__ cursor,
                                               int* __restrict__ srcArr,
                                               int N, int E, int B) {
    __shared__ int lcur[64];
    for (int b = blockIdx.x; b < B; b += gridDim.x) {
        const int base = pboff[b];
        const int end = (b == B - 1) ? E : pboff[b + 1];
        const int t = threadIdx.x;
        if (t < 64) {
            const int n = (b << 6) + t;
            lcur[t] = (n < N) ? cursor[n] : 0;
        }
        __syncthreads();
        for (int i = base + t; i < end; i += 256) {
            const int pk = pairs[i];
            const int pos = atomicAdd(&lcur[pk & 63], 1);
            srcArr[pos] = pk >> 6;
        }
        __syncthreads();
    }
}

// ---------------- GEMM: h = relu(x @ W1^T + b1), fused row-normalize ----------------
__global__ void __launch_bounds__(256) k_gemm(const float* __restrict__ x,
                                              const float* __restrict__ W1,
                                              const float* __restrict__ b1,
                                              float* __restrict__ hn,
                                              float* __restrict__ nrm, int N) {
    const int tid = threadIdx.x;
    const int j = tid & 15;
    const int n = blockIdx.x * 16 + (tid >> 4);
    if (n >= N) return;
    const float4* __restrict__ xr = reinterpret_cast<const float4*>(x + (size_t)n * DIM);
    const float4* __restrict__ wr = reinterpret_cast<const float4*>(W1 + (size_t)j * DIM);
    float acc = 0.f;
#pragma unroll 8
    for (int k = 0; k < DIM / 4; ++k) {
        acc += dot4(xr[k], wr[k]);
    }
    float v = fmaxf(acc + b1[j], 0.f);
    float s = v * v;
    s += __shfl_xor(s, 1, 64); s += __shfl_xor(s, 2, 64);
    s += __shfl_xor(s, 4, 64); s += __shfl_xor(s, 8, 64);
    float nc = fmaxf(sqrtf(s), 1e-12f);
    hn[(size_t)n * H + j] = v / nc;
    if (j == 0) nrm[n] = nc;
}

// ---------------- AGNN propagation ----------------
template <bool WRITE_HN, bool FIXED_BETA>
__global__ void __launch_bounds__(256) k_prop(
    const float* __restrict__ hn_in, const float* __restrict__ nrm_in,
    float* __restrict__ h_out, float* __restrict__ hn_out, float* __restrict__ nrm_out,
    const float* __restrict__ beta_ptr,
    const int* __restrict__ off, const int* __restrict__ cnt,
    const int* __restrict__ srcArr, int N) {
    const int lane = threadIdx.x & 63;
    const int n = blockIdx.x * 4 + (threadIdx.x >> 6);
    if (n >= N) return;
    const float beta = FIXED_BETA ? 1.0f : beta_ptr[0];
    const int start = off[n];
    const int c = cnt[n];
    const float4* __restrict__ hv = reinterpret_cast<const float4*>(hn_in);
    const size_t nb = (size_t)n * (H / 4);
    const float4 d0 = hv[nb + 0], d1 = hv[nb + 1], d2 = hv[nb + 2], d3 = hv[nb + 3];

    float acc[H];
#pragma unroll
    for (int i = 0; i < H; ++i) acc[i] = 0.f;
    float denom = 0.f;

    if (c <= 128) {
        const bool act1 = lane < c;
        const bool act2 = 64 + lane < c;
        int s1 = 0, s2 = 0;
        float4 a0 = {0,0,0,0}, a1 = {0,0,0,0}, a2 = {0,0,0,0}, a3 = {0,0,0,0};
        float4 g0 = {0,0,0,0}, g1 = {0,0,0,0}, g2 = {0,0,0,0}, g3 = {0,0,0,0};
        float al1 = -INFINITY, al2 = -INFINITY;
        if (act1) {
            s1 = srcArr[start + lane];
            const size_t sb = (size_t)s1 * (H / 4);
            a0 = hv[sb + 0]; a1 = hv[sb + 1]; a2 = hv[sb + 2]; a3 = hv[sb + 3];
            al1 = beta * (dot4(a0, d0) + dot4(a1, d1) + dot4(a2, d2) + dot4(a3, d3));
        }
        if (act2) {
            s2 = srcArr[start + 64 + lane];
            const size_t sb = (size_t)s2 * (H / 4);
            g0 = hv[sb + 0]; g1 = hv[sb + 1]; g2 = hv[sb + 2]; g3 = hv[sb + 3];
            al2 = beta * (dot4(g0, d0) + dot4(g1, d1) + dot4(g2, d2) + dot4(g3, d3));
        }
        const float m = waveMax(fmaxf(al1, al2));
        float ex1 = 0.f, ex2 = 0.f, w1 = 0.f, w2 = 0.f;
        if (act1) { ex1 = __expf(al1 - m); w1 = ex1 * nrm_in[s1]; }
        if (act2) { ex2 = __expf(al2 - m); w2 = ex2 * nrm_in[s2]; }
        denom = ex1 + ex2;
        acc[0]  = w1 * a0.x + w2 * g0.x;  acc[1]  = w1 * a0.y + w2 * g0.y;
        acc[2]  = w1 * a0.z + w2 * g0.z;  acc[3]  = w1 * a0.w + w2 * g0.w;
        acc[4]  = w1 * a1.x + w2 * g1.x;  acc[5]  = w1 * a1.y + w2 * g1.y;
        acc[6]  = w1 * a1.z + w2 * g1.z;  acc[7]  = w1 * a1.w + w2 * g1.w;
        acc[8]  = w1 * a2.x + w2 * g2.x;  acc[9]  = w1 * a2.y + w2 * g2.y;
        acc[10] = w1 * a2.z + w2 * g2.z;  acc[11] = w1 * a2.w + w2 * g2.w;
        acc[12] = w1 * a3.x + w2 * g3.x;  acc[13] = w1 * a3.y + w2 * g3.y;
        acc[14] = w1 * a3.z + w2 * g3.z;  acc[15] = w1 * a3.w + w2 * g3.w;
    } else {
        float m = -INFINITY;
        for (int e0 = 0; e0 < c; e0 += 64) {
            if (e0 + lane < c) {
                const int s = srcArr[start + e0 + lane];
                const size_t sb = (size_t)s * (H / 4);
                float4 a0 = hv[sb + 0], a1 = hv[sb + 1], a2 = hv[sb + 2], a3 = hv[sb + 3];
                m = fmaxf(m, beta * (dot4(a0, d0) + dot4(a1, d1) + dot4(a2, d2) + dot4(a3, d3)));
            }
        }
        m = waveMax(m);
        for (int e0 = 0; e0 < c; e0 += 64) {
            if (e0 + lane < c) {
                const int s = srcArr[start + e0 + lane];
                const size_t sb = (size_t)s * (H / 4);
                float4 a0 = hv[sb + 0], a1 = hv[sb + 1], a2 = hv[sb + 2], a3 = hv[sb + 3];
                float al = beta * (dot4(a0, d0) + dot4(a1, d1) + dot4(a2, d2) + dot4(a3, d3));
                float ex = __expf(al - m);
                denom += ex;
                float wv = ex * nrm_in[s];
                acc[0]  += wv * a0.x; acc[1]  += wv * a0.y; acc[2]  += wv * a0.z; acc[3]  += wv * a0.w;
                acc[4]  += wv * a1.x; acc[5]  += wv * a1.y; acc[6]  += wv * a1.z; acc[7]  += wv * a1.w;
                acc[8]  += wv * a2.x; acc[9]  += wv * a2.y; acc[10] += wv * a2.z; acc[11] += wv * a2.w;
                acc[12] += wv * a3.x; acc[13] += wv * a3.y; acc[14] += wv * a3.z; acc[15] += wv * a3.w;
            }
        }
    }
    denom = waveSum(denom);

    // reduce-scatter: 16 features x 64 lanes -> one feature per lane (static indices only)
#pragma unroll
    for (int i = 0; i < 8; ++i) {
        const float snd  = (lane & 1) ? acc[i] : acc[i + 8];
        const float keep = (lane & 1) ? acc[i + 8] : acc[i];
        acc[i] = keep + __shfl_xor(snd, 1, 64);
    }
#pragma unroll
    for (int i = 0; i < 4; ++i) {
        const float snd  = (lane & 2) ? acc[i] : acc[i + 4];
        const float keep = (lane & 2) ? acc[i + 4] : acc[i];
        acc[i] = keep + __shfl_xor(snd, 2, 64);
    }
#pragma unroll
    for (int i = 0; i < 2; ++i) {
        const float snd  = (lane & 4) ? acc[i] : acc[i + 2];
        const float keep = (lane & 4) ? acc[i + 2] : acc[i];
        acc[i] = keep + __shfl_xor(snd, 4, 64);
    }
    {
        const float snd  = (lane & 8) ? acc[0] : acc[1];
        const float keep = (lane & 8) ? acc[1] : acc[0];
        acc[0] = keep + __shfl_xor(snd, 8, 64);
    }
    float v = acc[0];
    v += __shfl_xor(v, 16, 64);
    v += __shfl_xor(v, 32, 64);
    const float o = v / denom;
    const int f = ((lane & 1) << 3) | ((lane & 2) << 1) | ((lane & 4) >> 1) | ((lane & 8) >> 3);

    if (WRITE_HN) {
        float q = o * o;
        q += __shfl_xor(q, 1, 64); q += __shfl_xor(q, 2, 64);
        q += __shfl_xor(q, 4, 64); q += __shfl_xor(q, 8, 64);
        const float nc = fmaxf(sqrtf(q), 1e-12f);
        if (lane < 16) hn_out[(size_t)n * H + f] = o / nc;
        if (lane == 0) nrm_out[n] = nc;
    } else {
        if (lane < 16) h_out[(size_t)n * H + f] = o;
    }
}

// ---------------- output: log_softmax(h3 @ W2^T + b2) ----------------
__global__ void __launch_bounds__(256) k_out(const float* __restrict__ h3,
                                             const float* __restrict__ W2,
                                             const float* __restrict__ b2,
                                             float* __restrict__ out, int N) {
    const int lane = threadIdx.x & 63;
    const int n = blockIdx.x * 4 + (threadIdx.x >> 6);
    if (n >= N) return;
    const float4* __restrict__ hv = reinterpret_cast<const float4*>(h3 + (size_t)n * H);
    const float4 h0 = hv[0], h1 = hv[1], h2 = hv[2], h3v = hv[3];
    float logit = -INFINITY;
    if (lane < NC) {
        const float4* __restrict__ wr = reinterpret_cast<const float4*>(W2 + (size_t)lane * H);
        logit = b2[lane] + dot4(h0, wr[0]) + dot4(h1, wr[1]) + dot4(h2, wr[2]) + dot4(h3v, wr[3]);
    }
    const float m = waveMax(logit);
    const float ex = (lane < NC) ? __expf(logit - m) : 0.f;
    const float s = waveSum(ex);
    if (lane < NC) out[(size_t)n * NC + lane] = logit - m - logf(s);
}

extern "C" void kernel_launch(void* const* d_in, const int* in_sizes, int n_in,
                              void* d_out, int out_size, void* d_ws, size_t ws_size,
                              hipStream_t stream) {
    const float* x     = (const float*)d_in[0];
    const int*   ei    = (const int*)d_in[1];
    const float* W1    = (const float*)d_in[2];
    const float* b1    = (const float*)d_in[3];
    const float* W2    = (const float*)d_in[4];
    const float* b2    = (const float*)d_in[5];
    const float* beta2 = (const float*)d_in[6];
    float* out = (float*)d_out;

    const int N  = in_sizes[0] / DIM;
    const int E  = in_sizes[1] / 2;
    const int E2 = E + N;
    const int NB = (N + 255) / 256;          // scan blocks (391 for N=100K, must be <=512)
    const int B  = (N + 63) / 64;            // dst buckets (1563)
    const int* src = ei;
    const int* dst = ei + E;

    char* w = (char*)d_ws;
    auto take = [&](size_t bytes) { char* p = w; w += (bytes + 255) & ~size_t(255); return p; };
    int*   cnt    = (int*)take((size_t)N * 4);
    int*   off    = (int*)take((size_t)N * 4);
    int*   cursor = (int*)take((size_t)N * 4);
    int*   bsum   = (int*)take((size_t)NB * 4);
    int*   bexc   = (int*)take((size_t)NB * 4);
    int*   pboff  = (int*)take((size_t)B * 4);
    int*   bcur   = (int*)take((size_t)B * 4);
    int*   srcArr = (int*)take((size_t)E2 * 4);
    int*   pairs  = (int*)take((size_t)E * 4);
    float* hn1    = (float*)take((size_t)N * H * 4);
    float* nr1    = (float*)take((size_t)N * 4);
    float* hn2    = (float*)take((size_t)N * H * 4);
    float* nr2    = (float*)take((size_t)N * 4);
    float* h3     = (float*)take((size_t)N * H * 4);
    (void)ws_size; (void)n_in; (void)out_size;

    hipMemsetAsync(cnt, 0, (size_t)N * sizeof(int), stream);
    k_hist<<<2048, 256, 0, stream>>>(dst, cnt, E);
    k_scan1<<<NB, 256, 0, stream>>>(cnt, bsum, N);
    k_scan2<<<1, 512, 0, stream>>>(bsum, bexc, NB);
    k_scan3<<<NB, 256, 0, stream>>>(cnt, bexc, off, cursor, srcArr, pboff, bcur, N);
    k_binpass<<<2048, 256, 0, stream>>>(src, dst, bcur, pairs, E);
    k_build<<<B, 256, 0, stream>>>(pboff, pairs, cursor, srcArr, N, E, B);
    k_gemm<<<(N + 15) / 16, 256, 0, stream>>>(x, W1, b1, hn1, nr1, N);
    k_prop<true, true><<<(N + 3) / 4, 256, 0, stream>>>(
        hn1, nr1, nullptr, hn2, nr2, nullptr, off, cnt, srcArr, N);
    k_prop<false, false><<<(N + 3) / 4, 256, 0, stream>>>(
        hn2, nr2, h3, nullptr, nullptr, beta2, off, cnt, srcArr, N);
    k_out<<<(N + 3) / 4, 256, 0, stream>>>(h3, W2, b2, out, N);
}

// Round 7
// 1150.940 us; speedup vs baseline: 1.8723x; 1.8723x over previous
//
#include <hip/hip_runtime.h>
#include <math.h>

static constexpr int DIM  = 512;   // input feature dim
static constexpr int H    = 16;    // hidden dim
static constexpr int NC   = 40;    // classes
static constexpr int TILE = 32768; // edges per partition tile
static constexpr int BCAP = 2048;  // max dst-buckets (N <= 131072)

__device__ __forceinline__ float dot4(float4 a, float4 b) {
    return a.x * b.x + a.y * b.y + a.z * b.z + a.w * b.w;
}
__device__ __forceinline__ float waveMax(float v) {
#pragma unroll
    for (int m = 1; m <= 32; m <<= 1) v = fmaxf(v, __shfl_xor(v, m, 64));
    return v;
}
__device__ __forceinline__ float waveSum(float v) {
#pragma unroll
    for (int m = 1; m <= 32; m <<= 1) v += __shfl_xor(v, m, 64);
    return v;
}

// ---------------- CSR build: tile-private counting sort (no global atomics) ----------------

// per-tile LDS histogram over dst>>6 buckets -> histT[b*T + t]
__global__ void __launch_bounds__(256) k_tilehist(const int* __restrict__ dst,
                                                  int* __restrict__ histT,
                                                  int E, int T, int B) {
    __shared__ int h[BCAP];
    const int t = threadIdx.x;
    for (int i = t; i < B; i += 256) h[i] = 0;
    __syncthreads();
    const int e0 = blockIdx.x * TILE;
    const int e1 = min(e0 + TILE, E);
    for (int i = e0 + t; i < e1; i += 256) atomicAdd(&h[dst[i] >> 6], 1);
    __syncthreads();
    for (int i = t; i < B; i += 256) histT[(size_t)i * T + blockIdx.x] = h[i];
}

// block sums over 256-element chunks of histT (length M)
__global__ void __launch_bounds__(256) k_scan1(const int* __restrict__ a,
                                               int* __restrict__ bsum, int M) {
    __shared__ int sd[256];
    const int t = threadIdx.x;
    const int i = blockIdx.x * 256 + t;
    sd[t] = (i < M) ? a[i] : 0;
    __syncthreads();
    for (int s = 128; s > 0; s >>= 1) {
        if (t < s) sd[t] += sd[t + s];
        __syncthreads();
    }
    if (t == 0) bsum[blockIdx.x] = sd[0];
}

// single-block exclusive scan of NBb block sums (NBb <= 256*P, serial chunks)
__global__ void __launch_bounds__(256) k_scan2(const int* __restrict__ bsum,
                                               int* __restrict__ bexc, int NBb) {
    __shared__ int sd[256];
    const int t = threadIdx.x;
    const int P = (NBb + 255) / 256;
    int s = 0;
    for (int k = 0; k < P; ++k) {
        const int i = t * P + k;
        if (i < NBb) s += bsum[i];
    }
    sd[t] = s;
    __syncthreads();
    for (int ofs = 1; ofs < 256; ofs <<= 1) {
        const int y = (t >= ofs) ? sd[t - ofs] : 0;
        __syncthreads();
        sd[t] += y;
        __syncthreads();
    }
    int pre = sd[t] - s;  // exclusive prefix of this thread's chunk
    for (int k = 0; k < P; ++k) {
        const int i = t * P + k;
        if (i < NBb) { bexc[i] = pre; pre += bsum[i]; }
    }
}

// finish exclusive scan of histT in place
__global__ void __launch_bounds__(256) k_scan3(int* __restrict__ histT,
                                               const int* __restrict__ bexc, int M) {
    __shared__ int sd[256];
    const int t = threadIdx.x;
    const int i = blockIdx.x * 256 + t;
    const int v = (i < M) ? histT[i] : 0;
    sd[t] = v;
    __syncthreads();
    for (int ofs = 1; ofs < 256; ofs <<= 1) {
        const int y = (t >= ofs) ? sd[t - ofs] : 0;
        __syncthreads();
        sd[t] += y;
        __syncthreads();
    }
    if (i < M) histT[i] = sd[t] - v + bexc[blockIdx.x];
}

// scatter pass: re-read tile, write packed (src<<6)|(dst&63) into pre-reserved
// per-(bucket,tile) contiguous segments. LDS cursors only — zero global atomics.
__global__ void __launch_bounds__(256) k_scatter2(const int* __restrict__ src,
                                                  const int* __restrict__ dst,
                                                  const int* __restrict__ histT,
                                                  int* __restrict__ pairs,
                                                  int E, int T, int B) {
    __shared__ int cur[BCAP];
    const int t = threadIdx.x;
    for (int i = t; i < B; i += 256) cur[i] = histT[(size_t)i * T + blockIdx.x];
    __syncthreads();
    const int e0 = blockIdx.x * TILE;
    const int e1 = min(e0 + TILE, E);
    for (int i = e0 + t; i < e1; i += 256) {
        const int d = dst[i];
        const int s = src[i];
        const int p = atomicAdd(&cur[d >> 6], 1);
        pairs[p] = (s << 6) | (d & 63);
    }
}

// one block per bucket: derive per-node counts/offsets in-block, place self-loops,
// group pairs by node into the bucket's contiguous CSR slice (LDS cursors only)
__global__ void __launch_bounds__(256) k_build2(const int* __restrict__ histT,
                                                const int* __restrict__ pairs,
                                                int* __restrict__ srcArr,
                                                int* __restrict__ off,
                                                int* __restrict__ cnt,
                                                int N, int E, int T, int B) {
    __shared__ int ncnt[64];
    __shared__ int ncur[64];
    const int b = blockIdx.x;
    const int t = threadIdx.x;
    const int pstart = histT[(size_t)b * T];
    const int pend = (b + 1 < B) ? histT[(size_t)(b + 1) * T] : E;
    if (t < 64) ncnt[t] = 0;
    __syncthreads();
    for (int i = pstart + t; i < pend; i += 256) atomicAdd(&ncnt[pairs[i] & 63], 1);
    __syncthreads();
    if (t < 64) {
        const int v = ncnt[t];
        int inc = v;
#pragma unroll
        for (int ofs = 1; ofs < 64; ofs <<= 1) {
            const int y = __shfl_up(inc, ofs, 64);
            if (t >= ofs) inc += y;
        }
        const int n = (b << 6) + t;
        if (n < N) {
            const int o = pstart + (inc - v) + n;  // + n self-loops before node n
            off[n] = o;
            cnt[n] = v + 1;
            srcArr[o] = n;       // self-loop in slot 0
            ncur[t] = o + 1;
        }
    }
    __syncthreads();
    for (int i = pstart + t; i < pend; i += 256) {
        const int pk = pairs[i];
        const int pos = atomicAdd(&ncur[pk & 63], 1);
        srcArr[pos] = pk >> 6;
    }
}

// ---------------- GEMM: h = relu(x @ W1^T + b1), fused row-normalize ----------------
__global__ void __launch_bounds__(256) k_gemm(const float* __restrict__ x,
                                              const float* __restrict__ W1,
                                              const float* __restrict__ b1,
                                              float* __restrict__ hn,
                                              float* __restrict__ nrm, int N) {
    const int tid = threadIdx.x;
    const int j = tid & 15;
    const int n = blockIdx.x * 16 + (tid >> 4);
    if (n >= N) return;
    const float4* __restrict__ xr = reinterpret_cast<const float4*>(x + (size_t)n * DIM);
    const float4* __restrict__ wr = reinterpret_cast<const float4*>(W1 + (size_t)j * DIM);
    float acc = 0.f;
#pragma unroll 8
    for (int k = 0; k < DIM / 4; ++k) {
        acc += dot4(xr[k], wr[k]);
    }
    float v = fmaxf(acc + b1[j], 0.f);
    float s = v * v;
    s += __shfl_xor(s, 1, 64); s += __shfl_xor(s, 2, 64);
    s += __shfl_xor(s, 4, 64); s += __shfl_xor(s, 8, 64);
    float nc = fmaxf(sqrtf(s), 1e-12f);
    hn[(size_t)n * H + j] = v / nc;
    if (j == 0) nrm[n] = nc;
}

// ---------------- AGNN propagation ----------------
template <bool WRITE_HN, bool FIXED_BETA>
__global__ void __launch_bounds__(256) k_prop(
    const float* __restrict__ hn_in, const float* __restrict__ nrm_in,
    float* __restrict__ h_out, float* __restrict__ hn_out, float* __restrict__ nrm_out,
    const float* __restrict__ beta_ptr,
    const int* __restrict__ off, const int* __restrict__ cnt,
    const int* __restrict__ srcArr, int N) {
    const int lane = threadIdx.x & 63;
    const int n = blockIdx.x * 4 + (threadIdx.x >> 6);
    if (n >= N) return;
    const float beta = FIXED_BETA ? 1.0f : beta_ptr[0];
    const int start = off[n];
    const int c = cnt[n];
    const float4* __restrict__ hv = reinterpret_cast<const float4*>(hn_in);
    const size_t nb = (size_t)n * (H / 4);
    const float4 d0 = hv[nb + 0], d1 = hv[nb + 1], d2 = hv[nb + 2], d3 = hv[nb + 3];

    float acc[H];
#pragma unroll
    for (int i = 0; i < H; ++i) acc[i] = 0.f;
    float denom = 0.f;

    if (c <= 128) {
        const bool act1 = lane < c;
        const bool act2 = 64 + lane < c;
        int s1 = 0, s2 = 0;
        float4 a0 = {0,0,0,0}, a1 = {0,0,0,0}, a2 = {0,0,0,0}, a3 = {0,0,0,0};
        float4 g0 = {0,0,0,0}, g1 = {0,0,0,0}, g2 = {0,0,0,0}, g3 = {0,0,0,0};
        float al1 = -INFINITY, al2 = -INFINITY;
        if (act1) {
            s1 = srcArr[start + lane];
            const size_t sb = (size_t)s1 * (H / 4);
            a0 = hv[sb + 0]; a1 = hv[sb + 1]; a2 = hv[sb + 2]; a3 = hv[sb + 3];
            al1 = beta * (dot4(a0, d0) + dot4(a1, d1) + dot4(a2, d2) + dot4(a3, d3));
        }
        if (act2) {
            s2 = srcArr[start + 64 + lane];
            const size_t sb = (size_t)s2 * (H / 4);
            g0 = hv[sb + 0]; g1 = hv[sb + 1]; g2 = hv[sb + 2]; g3 = hv[sb + 3];
            al2 = beta * (dot4(g0, d0) + dot4(g1, d1) + dot4(g2, d2) + dot4(g3, d3));
        }
        const float m = waveMax(fmaxf(al1, al2));
        float ex1 = 0.f, ex2 = 0.f, w1 = 0.f, w2 = 0.f;
        if (act1) { ex1 = __expf(al1 - m); w1 = ex1 * nrm_in[s1]; }
        if (act2) { ex2 = __expf(al2 - m); w2 = ex2 * nrm_in[s2]; }
        denom = ex1 + ex2;
        acc[0]  = w1 * a0.x + w2 * g0.x;  acc[1]  = w1 * a0.y + w2 * g0.y;
        acc[2]  = w1 * a0.z + w2 * g0.z;  acc[3]  = w1 * a0.w + w2 * g0.w;
        acc[4]  = w1 * a1.x + w2 * g1.x;  acc[5]  = w1 * a1.y + w2 * g1.y;
        acc[6]  = w1 * a1.z + w2 * g1.z;  acc[7]  = w1 * a1.w + w2 * g1.w;
        acc[8]  = w1 * a2.x + w2 * g2.x;  acc[9]  = w1 * a2.y + w2 * g2.y;
        acc[10] = w1 * a2.z + w2 * g2.z;  acc[11] = w1 * a2.w + w2 * g2.w;
        acc[12] = w1 * a3.x + w2 * g3.x;  acc[13] = w1 * a3.y + w2 * g3.y;
        acc[14] = w1 * a3.z + w2 * g3.z;  acc[15] = w1 * a3.w + w2 * g3.w;
    } else {
        float m = -INFINITY;
        for (int e0 = 0; e0 < c; e0 += 64) {
            if (e0 + lane < c) {
                const int s = srcArr[start + e0 + lane];
                const size_t sb = (size_t)s * (H / 4);
                float4 a0 = hv[sb + 0], a1 = hv[sb + 1], a2 = hv[sb + 2], a3 = hv[sb + 3];
                m = fmaxf(m, beta * (dot4(a0, d0) + dot4(a1, d1) + dot4(a2, d2) + dot4(a3, d3)));
            }
        }
        m = waveMax(m);
        for (int e0 = 0; e0 < c; e0 += 64) {
            if (e0 + lane < c) {
                const int s = srcArr[start + e0 + lane];
                const size_t sb = (size_t)s * (H / 4);
                float4 a0 = hv[sb + 0], a1 = hv[sb + 1], a2 = hv[sb + 2], a3 = hv[sb + 3];
                float al = beta * (dot4(a0, d0) + dot4(a1, d1) + dot4(a2, d2) + dot4(a3, d3));
                float ex = __expf(al - m);
                denom += ex;
                float wv = ex * nrm_in[s];
                acc[0]  += wv * a0.x; acc[1]  += wv * a0.y; acc[2]  += wv * a0.z; acc[3]  += wv * a0.w;
                acc[4]  += wv * a1.x; acc[5]  += wv * a1.y; acc[6]  += wv * a1.z; acc[7]  += wv * a1.w;
                acc[8]  += wv * a2.x; acc[9]  += wv * a2.y; acc[10] += wv * a2.z; acc[11] += wv * a2.w;
                acc[12] += wv * a3.x; acc[13] += wv * a3.y; acc[14] += wv * a3.z; acc[15] += wv * a3.w;
            }
        }
    }
    denom = waveSum(denom);

    // reduce-scatter: 16 features x 64 lanes -> one feature per lane (static indices only)
#pragma unroll
    for (int i = 0; i < 8; ++i) {
        const float snd  = (lane & 1) ? acc[i] : acc[i + 8];
        const float keep = (lane & 1) ? acc[i + 8] : acc[i];
        acc[i] = keep + __shfl_xor(snd, 1, 64);
    }
#pragma unroll
    for (int i = 0; i < 4; ++i) {
        const float snd  = (lane & 2) ? acc[i] : acc[i + 4];
        const float keep = (lane & 2) ? acc[i + 4] : acc[i];
        acc[i] = keep + __shfl_xor(snd, 2, 64);
    }
#pragma unroll
    for (int i = 0; i < 2; ++i) {
        const float snd  = (lane & 4) ? acc[i] : acc[i + 2];
        const float keep = (lane & 4) ? acc[i + 2] : acc[i];
        acc[i] = keep + __shfl_xor(snd, 4, 64);
    }
    {
        const float snd  = (lane & 8) ? acc[0] : acc[1];
        const float keep = (lane & 8) ? acc[1] : acc[0];
        acc[0] = keep + __shfl_xor(snd, 8, 64);
    }
    float v = acc[0];
    v += __shfl_xor(v, 16, 64);
    v += __shfl_xor(v, 32, 64);
    const float o = v / denom;
    const int f = ((lane & 1) << 3) | ((lane & 2) << 1) | ((lane & 4) >> 1) | ((lane & 8) >> 3);

    if (WRITE_HN) {
        float q = o * o;
        q += __shfl_xor(q, 1, 64); q += __shfl_xor(q, 2, 64);
        q += __shfl_xor(q, 4, 64); q += __shfl_xor(q, 8, 64);
        const float nc = fmaxf(sqrtf(q), 1e-12f);
        if (lane < 16) hn_out[(size_t)n * H + f] = o / nc;
        if (lane == 0) nrm_out[n] = nc;
    } else {
        if (lane < 16) h_out[(size_t)n * H + f] = o;
    }
}

// ---------------- output: log_softmax(h3 @ W2^T + b2) ----------------
__global__ void __launch_bounds__(256) k_out(const float* __restrict__ h3,
                                             const float* __restrict__ W2,
                                             const float* __restrict__ b2,
                                             float* __restrict__ out, int N) {
    const int lane = threadIdx.x & 63;
    const int n = blockIdx.x * 4 + (threadIdx.x >> 6);
    if (n >= N) return;
    const float4* __restrict__ hv = reinterpret_cast<const float4*>(h3 + (size_t)n * H);
    const float4 h0 = hv[0], h1 = hv[1], h2 = hv[2], h3v = hv[3];
    float logit = -INFINITY;
    if (lane < NC) {
        const float4* __restrict__ wr = reinterpret_cast<const float4*>(W2 + (size_t)lane * H);
        logit = b2[lane] + dot4(h0, wr[0]) + dot4(h1, wr[1]) + dot4(h2, wr[2]) + dot4(h3v, wr[3]);
    }
    const float m = waveMax(logit);
    const float ex = (lane < NC) ? __expf(logit - m) : 0.f;
    const float s = waveSum(ex);
    if (lane < NC) out[(size_t)n * NC + lane] = logit - m - logf(s);
}

extern "C" void kernel_launch(void* const* d_in, const int* in_sizes, int n_in,
                              void* d_out, int out_size, void* d_ws, size_t ws_size,
                              hipStream_t stream) {
    const float* x     = (const float*)d_in[0];
    const int*   ei    = (const int*)d_in[1];
    const float* W1    = (const float*)d_in[2];
    const float* b1    = (const float*)d_in[3];
    const float* W2    = (const float*)d_in[4];
    const float* b2    = (const float*)d_in[5];
    const float* beta2 = (const float*)d_in[6];
    float* out = (float*)d_out;

    const int N   = in_sizes[0] / DIM;
    const int E   = in_sizes[1] / 2;
    const int E2  = E + N;
    const int T   = (E + TILE - 1) / TILE;   // 196 tiles
    const int B   = (N + 63) / 64;           // 1563 dst buckets (<= BCAP)
    const int M   = B * T;                   // scan length (~306K)
    const int NBb = (M + 255) / 256;
    const int* src = ei;
    const int* dst = ei + E;

    char* w = (char*)d_ws;
    auto take = [&](size_t bytes) { char* p = w; w += (bytes + 255) & ~size_t(255); return p; };
    int*   histT  = (int*)take((size_t)M * 4);
    int*   bsum   = (int*)take((size_t)NBb * 4);
    int*   bexc   = (int*)take((size_t)NBb * 4);
    int*   off    = (int*)take((size_t)N * 4);
    int*   cnt    = (int*)take((size_t)N * 4);
    int*   srcArr = (int*)take((size_t)E2 * 4);
    int*   pairs  = (int*)take((size_t)E * 4);
    float* hn1    = (float*)take((size_t)N * H * 4);
    float* nr1    = (float*)take((size_t)N * 4);
    float* hn2    = (float*)take((size_t)N * H * 4);
    float* nr2    = (float*)take((size_t)N * 4);
    float* h3     = (float*)take((size_t)N * H * 4);
    (void)ws_size; (void)n_in; (void)out_size;

    k_tilehist<<<T, 256, 0, stream>>>(dst, histT, E, T, B);
    k_scan1<<<NBb, 256, 0, stream>>>(histT, bsum, M);
    k_scan2<<<1, 256, 0, stream>>>(bsum, bexc, NBb);
    k_scan3<<<NBb, 256, 0, stream>>>(histT, bexc, M);
    k_scatter2<<<T, 256, 0, stream>>>(src, dst, histT, pairs, E, T, B);
    k_build2<<<B, 256, 0, stream>>>(histT, pairs, srcArr, off, cnt, N, E, T, B);
    k_gemm<<<(N + 15) / 16, 256, 0, stream>>>(x, W1, b1, hn1, nr1, N);
    k_prop<true, true><<<(N + 3) / 4, 256, 0, stream>>>(
        hn1, nr1, nullptr, hn2, nr2, nullptr, off, cnt, srcArr, N);
    k_prop<false, false><<<(N + 3) / 4, 256, 0, stream>>>(
        hn2, nr2, h3, nullptr, nullptr, beta2, off, cnt, srcArr, N);
    k_out<<<(N + 3) / 4, 256, 0, stream>>>(h3, W2, b2, out, N);
}

// Round 10
// 808.339 us; speedup vs baseline: 2.6659x; 1.4238x over previous
//
#include <hip/hip_runtime.h>
#include <math.h>

static constexpr int DIM  = 512;   // input feature dim
static constexpr int H    = 16;    // hidden dim
static constexpr int NC   = 40;    // classes
static constexpr int TILE = 32768; // edges per partition tile
static constexpr int BCAP = 2048;  // max dst-buckets (N <= 131072)

__device__ __forceinline__ float dot4(float4 a, float4 b) {
    return a.x * b.x + a.y * b.y + a.z * b.z + a.w * b.w;
}
__device__ __forceinline__ float waveMax(float v) {
#pragma unroll
    for (int m = 1; m <= 32; m <<= 1) v = fmaxf(v, __shfl_xor(v, m, 64));
    return v;
}
__device__ __forceinline__ float waveSum(float v) {
#pragma unroll
    for (int m = 1; m <= 32; m <<= 1) v += __shfl_xor(v, m, 64);
    return v;
}

// ---------------- CSR build: tile-private counting sort (no global atomics) ----------------

// per-tile LDS histogram over dst>>6 buckets -> histT[b*T + t]
__global__ void __launch_bounds__(256) k_tilehist(const int* __restrict__ dst,
                                                  int* __restrict__ histT,
                                                  int E, int T, int B) {
    __shared__ int h[BCAP];
    const int t = threadIdx.x;
    for (int i = t; i < B; i += 256) h[i] = 0;
    __syncthreads();
    const int e0 = blockIdx.x * TILE;
    const int e1 = min(e0 + TILE, E);
    for (int i = e0 + t; i < e1; i += 256) atomicAdd(&h[dst[i] >> 6], 1);
    __syncthreads();
    for (int i = t; i < B; i += 256) histT[(size_t)i * T + blockIdx.x] = h[i];
}

// block sums over 256-element chunks of histT (length M)
__global__ void __launch_bounds__(256) k_scan1(const int* __restrict__ a,
                                               int* __restrict__ bsum, int M) {
    __shared__ int sd[256];
    const int t = threadIdx.x;
    const int i = blockIdx.x * 256 + t;
    sd[t] = (i < M) ? a[i] : 0;
    __syncthreads();
    for (int s = 128; s > 0; s >>= 1) {
        if (t < s) sd[t] += sd[t + s];
        __syncthreads();
    }
    if (t == 0) bsum[blockIdx.x] = sd[0];
}

// single-block exclusive scan of NBb block sums (NBb <= 256*P, serial chunks)
__global__ void __launch_bounds__(256) k_scan2(const int* __restrict__ bsum,
                                               int* __restrict__ bexc, int NBb) {
    __shared__ int sd[256];
    const int t = threadIdx.x;
    const int P = (NBb + 255) / 256;
    int s = 0;
    for (int k = 0; k < P; ++k) {
        const int i = t * P + k;
        if (i < NBb) s += bsum[i];
    }
    sd[t] = s;
    __syncthreads();
    for (int ofs = 1; ofs < 256; ofs <<= 1) {
        const int y = (t >= ofs) ? sd[t - ofs] : 0;
        __syncthreads();
        sd[t] += y;
        __syncthreads();
    }
    int pre = sd[t] - s;  // exclusive prefix of this thread's chunk
    for (int k = 0; k < P; ++k) {
        const int i = t * P + k;
        if (i < NBb) { bexc[i] = pre; pre += bsum[i]; }
    }
}

// finish exclusive scan of histT in place
__global__ void __launch_bounds__(256) k_scan3(int* __restrict__ histT,
                                               const int* __restrict__ bexc, int M) {
    __shared__ int sd[256];
    const int t = threadIdx.x;
    const int i = blockIdx.x * 256 + t;
    const int v = (i < M) ? histT[i] : 0;
    sd[t] = v;
    __syncthreads();
    for (int ofs = 1; ofs < 256; ofs <<= 1) {
        const int y = (t >= ofs) ? sd[t - ofs] : 0;
        __syncthreads();
        sd[t] += y;
        __syncthreads();
    }
    if (i < M) histT[i] = sd[t] - v + bexc[blockIdx.x];
}

// scatter pass: re-read tile, write packed (src<<6)|(dst&63) into pre-reserved
// per-(bucket,tile) contiguous segments. LDS cursors only — zero global atomics.
__global__ void __launch_bounds__(256) k_scatter2(const int* __restrict__ src,
                                                  const int* __restrict__ dst,
                                                  const int* __restrict__ histT,
                                                  int* __restrict__ pairs,
                                                  int E, int T, int B) {
    __shared__ int cur[BCAP];
    const int t = threadIdx.x;
    for (int i = t; i < B; i += 256) cur[i] = histT[(size_t)i * T + blockIdx.x];
    __syncthreads();
    const int e0 = blockIdx.x * TILE;
    const int e1 = min(e0 + TILE, E);
    for (int i = e0 + t; i < e1; i += 256) {
        const int d = dst[i];
        const int s = src[i];
        const int p = atomicAdd(&cur[d >> 6], 1);
        pairs[p] = (s << 6) | (d & 63);
    }
}

// one block per bucket: derive per-node counts/offsets in-block, place self-loops,
// group pairs by node into the bucket's contiguous CSR slice (LDS cursors only)
__global__ void __launch_bounds__(256) k_build2(const int* __restrict__ histT,
                                                const int* __restrict__ pairs,
                                                int* __restrict__ srcArr,
                                                int* __restrict__ off,
                                                int* __restrict__ cnt,
                                                int N, int E, int T, int B) {
    __shared__ int ncnt[64];
    __shared__ int ncur[64];
    const int b = blockIdx.x;
    const int t = threadIdx.x;
    const int pstart = histT[(size_t)b * T];
    const int pend = (b + 1 < B) ? histT[(size_t)(b + 1) * T] : E;
    if (t < 64) ncnt[t] = 0;
    __syncthreads();
    for (int i = pstart + t; i < pend; i += 256) atomicAdd(&ncnt[pairs[i] & 63], 1);
    __syncthreads();
    if (t < 64) {
        const int v = ncnt[t];
        int inc = v;
#pragma unroll
        for (int ofs = 1; ofs < 64; ofs <<= 1) {
            const int y = __shfl_up(inc, ofs, 64);
            if (t >= ofs) inc += y;
        }
        const int n = (b << 6) + t;
        if (n < N) {
            const int o = pstart + (inc - v) + n;  // + n self-loops before node n
            off[n] = o;
            cnt[n] = v + 1;
            srcArr[o] = n;       // self-loop in slot 0
            ncur[t] = o + 1;
        }
    }
    __syncthreads();
    for (int i = pstart + t; i < pend; i += 256) {
        const int pk = pairs[i];
        const int pos = atomicAdd(&ncur[pk & 63], 1);
        srcArr[pos] = pk >> 6;
    }
}

// ---------------- GEMM: h = relu(x @ W1^T + b1), fused row-normalize ----------------
// one thread per node: x row streamed as float4 (per-lane sequential), W1 staged in
// LDS and read at wave-uniform addresses (free broadcast), 16 accumulators in VGPRs.
__global__ void __launch_bounds__(256) k_gemm(const float* __restrict__ x,
                                              const float* __restrict__ W1,
                                              const float* __restrict__ b1,
                                              float* __restrict__ hn,
                                              float* __restrict__ nrm, int N) {
    __shared__ float4 w[H][DIM / 4];   // 16 x 128 float4 = 32 KB
    __shared__ float bs[H];
    const int t = threadIdx.x;
    {
        const float4* __restrict__ wsrc = reinterpret_cast<const float4*>(W1);
        float4* wdst = &w[0][0];
        for (int i = t; i < H * (DIM / 4); i += 256) wdst[i] = wsrc[i];
        if (t < H) bs[t] = b1[t];
    }
    __syncthreads();
    const int n = blockIdx.x * 256 + t;
    if (n >= N) return;
    const float4* __restrict__ xr = reinterpret_cast<const float4*>(x + (size_t)n * DIM);
    float acc[H];
#pragma unroll
    for (int j = 0; j < H; ++j) acc[j] = 0.f;
#pragma unroll 4
    for (int k = 0; k < DIM / 4; ++k) {
        const float4 xc = xr[k];
#pragma unroll
        for (int j = 0; j < H; ++j) acc[j] += dot4(xc, w[j][k]);
    }
    float s = 0.f;
#pragma unroll
    for (int j = 0; j < H; ++j) {
        const float v = fmaxf(acc[j] + bs[j], 0.f);
        acc[j] = v;
        s += v * v;
    }
    const float nc = fmaxf(sqrtf(s), 1e-12f);
    const float inv = 1.f / nc;
    float4* __restrict__ ho = reinterpret_cast<float4*>(hn + (size_t)n * H);
#pragma unroll
    for (int j4 = 0; j4 < H / 4; ++j4) {
        float4 o;
        o.x = acc[j4 * 4 + 0] * inv;
        o.y = acc[j4 * 4 + 1] * inv;
        o.z = acc[j4 * 4 + 2] * inv;
        o.w = acc[j4 * 4 + 3] * inv;
        ho[j4] = o;
    }
    nrm[n] = nc;
}

// ---------------- AGNN propagation ----------------
template <bool WRITE_HN, bool FIXED_BETA>
__global__ void __launch_bounds__(256) k_prop(
    const float* __restrict__ hn_in, const float* __restrict__ nrm_in,
    float* __restrict__ h_out, float* __restrict__ hn_out, float* __restrict__ nrm_out,
    const float* __restrict__ beta_ptr,
    const int* __restrict__ off, const int* __restrict__ cnt,
    const int* __restrict__ srcArr, int N) {
    const int lane = threadIdx.x & 63;
    const int n = blockIdx.x * 4 + (threadIdx.x >> 6);
    if (n >= N) return;
    const float beta = FIXED_BETA ? 1.0f : beta_ptr[0];
    const int start = off[n];
    const int c = cnt[n];
    const float4* __restrict__ hv = reinterpret_cast<const float4*>(hn_in);
    const size_t nb = (size_t)n * (H / 4);
    const float4 d0 = hv[nb + 0], d1 = hv[nb + 1], d2 = hv[nb + 2], d3 = hv[nb + 3];

    float acc[H];
#pragma unroll
    for (int i = 0; i < H; ++i) acc[i] = 0.f;
    float denom = 0.f;

    if (c <= 128) {
        const bool act1 = lane < c;
        const bool act2 = 64 + lane < c;
        int s1 = 0, s2 = 0;
        float4 a0 = {0,0,0,0}, a1 = {0,0,0,0}, a2 = {0,0,0,0}, a3 = {0,0,0,0};
        float4 g0 = {0,0,0,0}, g1 = {0,0,0,0}, g2 = {0,0,0,0}, g3 = {0,0,0,0};
        float al1 = -INFINITY, al2 = -INFINITY;
        if (act1) {
            s1 = srcArr[start + lane];
            const size_t sb = (size_t)s1 * (H / 4);
            a0 = hv[sb + 0]; a1 = hv[sb + 1]; a2 = hv[sb + 2]; a3 = hv[sb + 3];
            al1 = beta * (dot4(a0, d0) + dot4(a1, d1) + dot4(a2, d2) + dot4(a3, d3));
        }
        if (act2) {
            s2 = srcArr[start + 64 + lane];
            const size_t sb = (size_t)s2 * (H / 4);
            g0 = hv[sb + 0]; g1 = hv[sb + 1]; g2 = hv[sb + 2]; g3 = hv[sb + 3];
            al2 = beta * (dot4(g0, d0) + dot4(g1, d1) + dot4(g2, d2) + dot4(g3, d3));
        }
        const float m = waveMax(fmaxf(al1, al2));
        float ex1 = 0.f, ex2 = 0.f, w1 = 0.f, w2 = 0.f;
        if (act1) { ex1 = __expf(al1 - m); w1 = ex1 * nrm_in[s1]; }
        if (act2) { ex2 = __expf(al2 - m); w2 = ex2 * nrm_in[s2]; }
        denom = ex1 + ex2;
        acc[0]  = w1 * a0.x + w2 * g0.x;  acc[1]  = w1 * a0.y + w2 * g0.y;
        acc[2]  = w1 * a0.z + w2 * g0.z;  acc[3]  = w1 * a0.w + w2 * g0.w;
        acc[4]  = w1 * a1.x + w2 * g1.x;  acc[5]  = w1 * a1.y + w2 * g1.y;
        acc[6]  = w1 * a1.z + w2 * g1.z;  acc[7]  = w1 * a1.w + w2 * g1.w;
        acc[8]  = w1 * a2.x + w2 * g2.x;  acc[9]  = w1 * a2.y + w2 * g2.y;
        acc[10] = w1 * a2.z + w2 * g2.z;  acc[11] = w1 * a2.w + w2 * g2.w;
        acc[12] = w1 * a3.x + w2 * g3.x;  acc[13] = w1 * a3.y + w2 * g3.y;
        acc[14] = w1 * a3.z + w2 * g3.z;  acc[15] = w1 * a3.w + w2 * g3.w;
    } else {
        float m = -INFINITY;
        for (int e0 = 0; e0 < c; e0 += 64) {
            if (e0 + lane < c) {
                const int s = srcArr[start + e0 + lane];
                const size_t sb = (size_t)s * (H / 4);
                float4 a0 = hv[sb + 0], a1 = hv[sb + 1], a2 = hv[sb + 2], a3 = hv[sb + 3];
                m = fmaxf(m, beta * (dot4(a0, d0) + dot4(a1, d1) + dot4(a2, d2) + dot4(a3, d3)));
            }
        }
        m = waveMax(m);
        for (int e0 = 0; e0 < c; e0 += 64) {
            if (e0 + lane < c) {
                const int s = srcArr[start + e0 + lane];
                const size_t sb = (size_t)s * (H / 4);
                float4 a0 = hv[sb + 0], a1 = hv[sb + 1], a2 = hv[sb + 2], a3 = hv[sb + 3];
                float al = beta * (dot4(a0, d0) + dot4(a1, d1) + dot4(a2, d2) + dot4(a3, d3));
                float ex = __expf(al - m);
                denom += ex;
                float wv = ex * nrm_in[s];
                acc[0]  += wv * a0.x; acc[1]  += wv * a0.y; acc[2]  += wv * a0.z; acc[3]  += wv * a0.w;
                acc[4]  += wv * a1.x; acc[5]  += wv * a1.y; acc[6]  += wv * a1.z; acc[7]  += wv * a1.w;
                acc[8]  += wv * a2.x; acc[9]  += wv * a2.y; acc[10] += wv * a2.z; acc[11] += wv * a2.w;
                acc[12] += wv * a3.x; acc[13] += wv * a3.y; acc[14] += wv * a3.z; acc[15] += wv * a3.w;
            }
        }
    }
    denom = waveSum(denom);

    // reduce-scatter: 16 features x 64 lanes -> one feature per lane (static indices only)
#pragma unroll
    for (int i = 0; i < 8; ++i) {
        const float snd  = (lane & 1) ? acc[i] : acc[i + 8];
        const float keep = (lane & 1) ? acc[i + 8] : acc[i];
        acc[i] = keep + __shfl_xor(snd, 1, 64);
    }
#pragma unroll
    for (int i = 0; i < 4; ++i) {
        const float snd  = (lane & 2) ? acc[i] : acc[i + 4];
        const float keep = (lane & 2) ? acc[i + 4] : acc[i];
        acc[i] = keep + __shfl_xor(snd, 2, 64);
    }
#pragma unroll
    for (int i = 0; i < 2; ++i) {
        const float snd  = (lane & 4) ? acc[i] : acc[i + 2];
        const float keep = (lane & 4) ? acc[i + 2] : acc[i];
        acc[i] = keep + __shfl_xor(snd, 4, 64);
    }
    {
        const float snd  = (lane & 8) ? acc[0] : acc[1];
        const float keep = (lane & 8) ? acc[1] : acc[0];
        acc[0] = keep + __shfl_xor(snd, 8, 64);
    }
    float v = acc[0];
    v += __shfl_xor(v, 16, 64);
    v += __shfl_xor(v, 32, 64);
    const float o = v / denom;
    const int f = ((lane & 1) << 3) | ((lane & 2) << 1) | ((lane & 4) >> 1) | ((lane & 8) >> 3);

    if (WRITE_HN) {
        float q = o * o;
        q += __shfl_xor(q, 1, 64); q += __shfl_xor(q, 2, 64);
        q += __shfl_xor(q, 4, 64); q += __shfl_xor(q, 8, 64);
        const float nc = fmaxf(sqrtf(q), 1e-12f);
        if (lane < 16) hn_out[(size_t)n * H + f] = o / nc;
        if (lane == 0) nrm_out[n] = nc;
    } else {
        if (lane < 16) h_out[(size_t)n * H + f] = o;
    }
}

// ---------------- output: log_softmax(h3 @ W2^T + b2) ----------------
__global__ void __launch_bounds__(256) k_out(const float* __restrict__ h3,
                                             const float* __restrict__ W2,
                                             const float* __restrict__ b2,
                                             float* __restrict__ out, int N) {
    const int lane = threadIdx.x & 63;
    const int n = blockIdx.x * 4 + (threadIdx.x >> 6);
    if (n >= N) return;
    const float4* __restrict__ hv = reinterpret_cast<const float4*>(h3 + (size_t)n * H);
    const float4 h0 = hv[0], h1 = hv[1], h2 = hv[2], h3v = hv[3];
    float logit = -INFINITY;
    if (lane < NC) {
        const float4* __restrict__ wr = reinterpret_cast<const float4*>(W2 + (size_t)lane * H);
        logit = b2[lane] + dot4(h0, wr[0]) + dot4(h1, wr[1]) + dot4(h2, wr[2]) + dot4(h3v, wr[3]);
    }
    const float m = waveMax(logit);
    const float ex = (lane < NC) ? __expf(logit - m) : 0.f;
    const float s = waveSum(ex);
    if (lane < NC) out[(size_t)n * NC + lane] = logit - m - logf(s);
}

extern "C" void kernel_launch(void* const* d_in, const int* in_sizes, int n_in,
                              void* d_out, int out_size, void* d_ws, size_t ws_size,
                              hipStream_t stream) {
    const float* x     = (const float*)d_in[0];
    const int*   ei    = (const int*)d_in[1];
    const float* W1    = (const float*)d_in[2];
    const float* b1    = (const float*)d_in[3];
    const float* W2    = (const float*)d_in[4];
    const float* b2    = (const float*)d_in[5];
    const float* beta2 = (const float*)d_in[6];
    float* out = (float*)d_out;

    const int N   = in_sizes[0] / DIM;
    const int E   = in_sizes[1] / 2;
    const int E2  = E + N;
    const int T   = (E + TILE - 1) / TILE;   // 196 tiles
    const int B   = (N + 63) / 64;           // 1563 dst buckets (<= BCAP)
    const int M   = B * T;                   // scan length (~306K)
    const int NBb = (M + 255) / 256;
    const int* src = ei;
    const int* dst = ei + E;

    char* w = (char*)d_ws;
    auto take = [&](size_t bytes) { char* p = w; w += (bytes + 255) & ~size_t(255); return p; };
    int*   histT  = (int*)take((size_t)M * 4);
    int*   bsum   = (int*)take((size_t)NBb * 4);
    int*   bexc   = (int*)take((size_t)NBb * 4);
    int*   off    = (int*)take((size_t)N * 4);
    int*   cnt    = (int*)take((size_t)N * 4);
    int*   srcArr = (int*)take((size_t)E2 * 4);
    int*   pairs  = (int*)take((size_t)E * 4);
    float* hn1    = (float*)take((size_t)N * H * 4);
    float* nr1    = (float*)take((size_t)N * 4);
    float* hn2    = (float*)take((size_t)N * H * 4);
    float* nr2    = (float*)take((size_t)N * 4);
    float* h3     = (float*)take((size_t)N * H * 4);
    (void)ws_size; (void)n_in; (void)out_size;

    k_tilehist<<<T, 256, 0, stream>>>(dst, histT, E, T, B);
    k_scan1<<<NBb, 256, 0, stream>>>(histT, bsum, M);
    k_scan2<<<1, 256, 0, stream>>>(bsum, bexc, NBb);
    k_scan3<<<NBb, 256, 0, stream>>>(histT, bexc, M);
    k_scatter2<<<T, 256, 0, stream>>>(src, dst, histT, pairs, E, T, B);
    k_build2<<<B, 256, 0, stream>>>(histT, pairs, srcArr, off, cnt, N, E, T, B);
    k_gemm<<<(N + 255) / 256, 256, 0, stream>>>(x, W1, b1, hn1, nr1, N);
    k_prop<true, true><<<(N + 3) / 4, 256, 0, stream>>>(
        hn1, nr1, nullptr, hn2, nr2, nullptr, off, cnt, srcArr, N);
    k_prop<false, false><<<(N + 3) / 4, 256, 0, stream>>>(
        hn2, nr2, h3, nullptr, nullptr, beta2, off, cnt, srcArr, N);
    k_out<<<(N + 3) / 4, 256, 0, stream>>>(h3, W2, b2, out, N);
}